// Round 14
// baseline (171.013 us; speedup 1.0000x reference)
//
#include <hip/hip_runtime.h>
#include <hip/hip_bf16.h>

#define BLK 256
#define NBS 64             // scatter blocks (bounds reservation-chain length)
#define BIN_SHIFT 8        // 256 nodes per bin
#define BCAP 4608          // fixed per-bin edge capacity (mean 4082, +8 sigma)

typedef unsigned short ushort_t;
typedef unsigned int uint_t;
typedef unsigned long long ull_t;
typedef __attribute__((ext_vector_type(8))) short bf16x8;
typedef __attribute__((ext_vector_type(4))) float f32x4;

static __device__ __forceinline__ float bf2f(ushort_t u) {
    return __uint_as_float((uint_t)u << 16);
}
static __device__ __forceinline__ ushort_t f2bf(float f) {
    __hip_bfloat16 h = __float2bfloat16(f);   // RNE
    return *reinterpret_cast<ushort_t*>(&h);
}

// ================= R13 preprocessing restructure =================
// Fixed-capacity bins (BCAP) + global atomic bulk-reservation kill the whole
// bcnt/ebofs/scan chain (R12: 3 dispatches + 100k-entry table). 64 scatter
// blocks LDS-count their chunk, reserve per-bin space with ONE atomicAdd per
// (block,bin), then scatter. CSR is fixed-stride per bin; rowbeg+rcnt replace
// rowptr. gcnt zeroed via tiny hipMemsetAsync (graph-capturable).
// Normalization stays factorized (R12): H' = dinv*(G@W), csr_val = w*dinv[d].

// ---------------- scatter + weight conversion (one dispatch) ----------------

__global__ __launch_bounds__(256) void k_scatter(const int* __restrict__ eidx,
                                                 const float* __restrict__ ea,
                                                 int* __restrict__ gcnt,
                                                 uint2* __restrict__ binned,
                                                 int nbins, int E,
                                                 const float* __restrict__ W1, ushort_t* __restrict__ Wt1,
                                                 const float* __restrict__ W2, ushort_t* __restrict__ Wt2,
                                                 const float* __restrict__ W3, ushort_t* __restrict__ Wt3) {
    const int b = blockIdx.x;
    const int t = threadIdx.x;
    if (b < NBS) {
        __shared__ int h[256];
        __shared__ int sbase[256];
        h[t] = 0;
        __syncthreads();
        // pass 1: count my grid-strided chunk
        for (int e = b * BLK + t; e < E; e += NBS * BLK)
            atomicAdd(&h[eidx[E + e] >> BIN_SHIFT], 1);
        __syncthreads();
        // bulk-reserve per-bin space (chains of <=NBS per address)
        if (t < nbins) sbase[t] = atomicAdd(&gcnt[t], h[t]);
        h[t] = 0;
        __syncthreads();
        // pass 2: scatter (packed 8B: (s<<8)|(d&255), w)
        for (int e = b * BLK + t; e < E; e += NBS * BLK) {
            int s = eidx[e];
            int d = eidx[E + e];
            float w = ea[e];
            int bin = d >> BIN_SHIFT;
            int r = sbase[bin] + atomicAdd(&h[bin], 1);
            if (r < BCAP)   // overflow beyond +8sigma: drop (never expected)
                binned[(size_t)bin * BCAP + r] =
                    make_uint2(((uint_t)s << 8) | (uint_t)(d & 255), __float_as_uint(w));
        }
    } else {
        int j = (b - NBS) * 256 + t;   // W[fin][fout] -> Wt[fout][fin] bf16
        if (j < 128 * 128) {
            int r = j / 128, c = j % 128;
            Wt1[(size_t)c * 128 + r] = f2bf(W1[j]);
        } else if (j < 128 * 128 + 128 * 64) {
            j -= 128 * 128;
            int r = j / 64, c = j % 64;
            Wt2[(size_t)c * 128 + r] = f2bf(W2[j]);
        } else if (j < 128 * 128 + 128 * 64 + 64 * 32) {
            j -= 128 * 128 + 128 * 64;
            int r = j / 32, c = j % 32;
            Wt3[(size_t)c * 64 + r] = f2bf(W3[j]);
        }
    }
}

// ---------------- fused per-bin hist + rowbeg/rcnt + dinv + CSR emit ----------------
// Stages the bin's packed edges in LDS (one global read), u64 packed hist
// (cnt | fixed-point weighted deg), LDS scan -> rowbeg, then emits CSR from LDS
// into the bin's fixed-stride region. csr_val = w * dinv[d].

__global__ __launch_bounds__(256) void k_bin_finish(const uint2* __restrict__ binned,
                                                    const int* __restrict__ gcnt,
                                                    float* __restrict__ dinv,
                                                    int* __restrict__ rowbeg,
                                                    int* __restrict__ rcnt,
                                                    int* __restrict__ csr_src,
                                                    float* __restrict__ csr_val,
                                                    int N) {
    __shared__ uint2 stage[BCAP];   // 36 KB
    __shared__ ull_t hs[256];
    __shared__ int   sc[256];
    __shared__ int   rp[256];
    __shared__ float dl[256];
    __shared__ int   c2[256];
    const int t = threadIdx.x;
    const int b = blockIdx.x;
    hs[t] = 0ull;
    c2[t] = 0;
    __syncthreads();
    const int cnt = min(gcnt[b], BCAP);
    const size_t base = (size_t)b * BCAP;

    // phase 1: LDS staging + histogram
    for (int i = t; i < cnt; i += 256) {
        uint2 p = binned[base + i];
        stage[i] = p;
        atomicAdd(&hs[p.x & 255],
                  (1ull << 40) | (ull_t)(__uint_as_float(p.y) * 4294967296.0f));
    }
    __syncthreads();

    // scan counts -> per-node offsets within the bin's fixed CSR region; dinv
    int v = (int)(hs[t] >> 40);
    sc[t] = v;
    __syncthreads();
    for (int off = 1; off < 256; off <<= 1) {
        int x = (t >= off) ? sc[t - off] : 0;
        __syncthreads();
        sc[t] += x;
        __syncthreads();
    }
    {
        ull_t s = hs[t];
        float dg = 1.0f + (float)(s & ((1ull << 40) - 1)) * (1.0f / 4294967296.0f);
        float di = rsqrtf(dg);
        dl[t] = di;
        rp[t] = (int)base + sc[t] - v;
        const int node = (b << BIN_SHIFT) + t;
        if (node < N) {
            dinv[node]   = di;
            rowbeg[node] = rp[t];
            rcnt[node]   = v;
        }
    }
    __syncthreads();

    // phase 2: emit from LDS into the bin's contiguous CSR region
    for (int i = t; i < cnt; i += 256) {
        uint2 p = stage[i];
        int d8 = p.x & 255;
        int r = atomicAdd(&c2[d8], 1);
        int pos = rp[d8] + r;
        csr_src[pos] = (int)(p.x >> 8);
        csr_val[pos] = __uint_as_float(p.y) * dl[d8];
    }
}

// ---------------- MFMA GEMM: C[n,FOUT](bf16) = dinv * (A[n,FIN] @ Wt^T) ----------------
// 32 rows/wave; mfma_f32_16x16x32_bf16; A-frag row=lane&15 k=(lane>>4)*8+j;
// B-frag col=lane&15; C/D col=lane&15 row=(lane>>4)*4+reg (m89-verified).
// AF32: layer 1 reads f32 x directly (in-register bf16 cvt).
// Epilogue scales each output row by dinv[row] (normalization factorization).

template <int FIN, int FOUT, bool AF32>
__global__ __launch_bounds__(256) void k_gemm_mfma(const void* __restrict__ Av,
                                                   const ushort_t* __restrict__ Wt,
                                                   const float* __restrict__ dinv,
                                                   ushort_t* __restrict__ C, int n) {
    constexpr int NT = FOUT / 16;      // col tiles
    constexpr int NK = FIN / 32;       // K steps
    const int wave = threadIdx.x >> 6;
    const int lane = threadIdx.x & 63;
    const int r0 = (blockIdx.x * 4 + wave) * 32;
    if (r0 >= n) return;

    const int l15 = lane & 15;
    const int kg  = lane >> 4;
    const int arow0 = min(r0 + l15, n - 1);        // tail clamp; bad rows never stored
    const int arow1 = min(r0 + 16 + l15, n - 1);

    f32x4 acc0[NT], acc1[NT];
#pragma unroll
    for (int c = 0; c < NT; ++c) { acc0[c] = (f32x4)(0.0f); acc1[c] = (f32x4)(0.0f); }

    const ushort_t* Bp = Wt + (size_t)l15 * FIN + kg * 8;

#pragma unroll 1   // keep rolled: full unroll hoists all B loads -> spill (R1 lesson)
    for (int ks = 0; ks < NK; ++ks) {
        bf16x8 a0, a1;
        if (AF32) {
            const float* A = (const float*)Av;
            const float* p0 = A + (size_t)arow0 * FIN + kg * 8 + ks * 32;
            const float* p1 = A + (size_t)arow1 * FIN + kg * 8 + ks * 32;
            float4 u0 = *(const float4*)p0, u1 = *(const float4*)(p0 + 4);
            float4 w0 = *(const float4*)p1, w1 = *(const float4*)(p1 + 4);
            a0[0] = (short)f2bf(u0.x); a0[1] = (short)f2bf(u0.y);
            a0[2] = (short)f2bf(u0.z); a0[3] = (short)f2bf(u0.w);
            a0[4] = (short)f2bf(u1.x); a0[5] = (short)f2bf(u1.y);
            a0[6] = (short)f2bf(u1.z); a0[7] = (short)f2bf(u1.w);
            a1[0] = (short)f2bf(w0.x); a1[1] = (short)f2bf(w0.y);
            a1[2] = (short)f2bf(w0.z); a1[3] = (short)f2bf(w0.w);
            a1[4] = (short)f2bf(w1.x); a1[5] = (short)f2bf(w1.y);
            a1[6] = (short)f2bf(w1.z); a1[7] = (short)f2bf(w1.w);
        } else {
            const ushort_t* A = (const ushort_t*)Av;
            a0 = *(const bf16x8*)(A + (size_t)arow0 * FIN + kg * 8 + ks * 32);
            a1 = *(const bf16x8*)(A + (size_t)arow1 * FIN + kg * 8 + ks * 32);
        }
#pragma unroll
        for (int c = 0; c < NT; ++c) {
            bf16x8 bfr = *(const bf16x8*)(Bp + (size_t)c * 16 * FIN + ks * 32);
            acc0[c] = __builtin_amdgcn_mfma_f32_16x16x32_bf16(a0, bfr, acc0[c], 0, 0, 0);
            acc1[c] = __builtin_amdgcn_mfma_f32_16x16x32_bf16(a1, bfr, acc1[c], 0, 0, 0);
        }
    }

#pragma unroll
    for (int g = 0; g < 2; ++g) {
        const int rbase = r0 + g * 16 + kg * 4;
#pragma unroll
        for (int j = 0; j < 4; ++j) {
            int row = rbase + j;
            if (row < n) {
                float dscale = dinv[row];
#pragma unroll
                for (int c = 0; c < NT; ++c) {
                    float val = (g == 0) ? acc0[c][j] : acc1[c][j];
                    C[(size_t)row * FOUT + c * 16 + l15] = f2bf(val * dscale);
                }
            }
        }
    }
}

// ---------------- aggregation (bf16 H', ushort4 gathers, x8-unrolled) ----------------
// out = dinv[node]*H'[node] + sum_e csr_val*H'[src] + b   (H' has dinv folded in)
// edge range: [rowbeg[node], rowbeg[node]+rcnt[node])

template <int FOUT, bool RELU, bool OBF16>
__global__ __launch_bounds__(256) void k_agg(const ushort_t* __restrict__ H,
                                             const float* __restrict__ dinv,
                                             const int* __restrict__ rowbeg,
                                             const int* __restrict__ rcnt,
                                             const int* __restrict__ csr_src,
                                             const float* __restrict__ csr_val,
                                             const float* __restrict__ bias,
                                             void* __restrict__ outv, int n) {
    constexpr int LPN = FOUT / 4;          // lanes per node: 32 / 16 / 8
    constexpr int NPW = 64 / LPN;          // nodes per wave: 2 / 4 / 8
    const int wave = threadIdx.x >> 6;
    const int lane = threadIdx.x & 63;
    const int sub  = lane / LPN;
    const int f4   = lane % LPN;           // feature-quad index
    const int node = (blockIdx.x * 4 + wave) * NPW + sub;
    if (node >= n) return;

    const ushort_t* __restrict__ Hf = H + 4 * f4;   // lane-fixed column base

    const float sn = dinv[node];
    ushort4 hv = *(const ushort4*)(Hf + (size_t)node * FOUT);
    float a0 = sn * bf2f(hv.x);
    float a1 = sn * bf2f(hv.y);
    float a2 = sn * bf2f(hv.z);
    float a3 = sn * bf2f(hv.w);

    const int e0 = rowbeg[node], e1 = e0 + rcnt[node];
    int e = e0;
    for (; e + 8 <= e1; e += 8) {
        int   s0 = csr_src[e+0], s1 = csr_src[e+1], s2 = csr_src[e+2], s3 = csr_src[e+3];
        int   s4 = csr_src[e+4], s5 = csr_src[e+5], s6 = csr_src[e+6], s7 = csr_src[e+7];
        float v0 = csr_val[e+0], v1 = csr_val[e+1], v2 = csr_val[e+2], v3 = csr_val[e+3];
        float v4 = csr_val[e+4], v5 = csr_val[e+5], v6 = csr_val[e+6], v7 = csr_val[e+7];
        ushort4 m0 = *(const ushort4*)(Hf + (size_t)s0 * FOUT);
        ushort4 m1 = *(const ushort4*)(Hf + (size_t)s1 * FOUT);
        ushort4 m2 = *(const ushort4*)(Hf + (size_t)s2 * FOUT);
        ushort4 m3 = *(const ushort4*)(Hf + (size_t)s3 * FOUT);
        ushort4 m4 = *(const ushort4*)(Hf + (size_t)s4 * FOUT);
        ushort4 m5 = *(const ushort4*)(Hf + (size_t)s5 * FOUT);
        ushort4 m6 = *(const ushort4*)(Hf + (size_t)s6 * FOUT);
        ushort4 m7 = *(const ushort4*)(Hf + (size_t)s7 * FOUT);
        a0 += v0 * bf2f(m0.x); a1 += v0 * bf2f(m0.y); a2 += v0 * bf2f(m0.z); a3 += v0 * bf2f(m0.w);
        a0 += v1 * bf2f(m1.x); a1 += v1 * bf2f(m1.y); a2 += v1 * bf2f(m1.z); a3 += v1 * bf2f(m1.w);
        a0 += v2 * bf2f(m2.x); a1 += v2 * bf2f(m2.y); a2 += v2 * bf2f(m2.z); a3 += v2 * bf2f(m2.w);
        a0 += v3 * bf2f(m3.x); a1 += v3 * bf2f(m3.y); a2 += v3 * bf2f(m3.z); a3 += v3 * bf2f(m3.w);
        a0 += v4 * bf2f(m4.x); a1 += v4 * bf2f(m4.y); a2 += v4 * bf2f(m4.z); a3 += v4 * bf2f(m4.w);
        a0 += v5 * bf2f(m5.x); a1 += v5 * bf2f(m5.y); a2 += v5 * bf2f(m5.z); a3 += v5 * bf2f(m5.w);
        a0 += v6 * bf2f(m6.x); a1 += v6 * bf2f(m6.y); a2 += v6 * bf2f(m6.z); a3 += v6 * bf2f(m6.w);
        a0 += v7 * bf2f(m7.x); a1 += v7 * bf2f(m7.y); a2 += v7 * bf2f(m7.z); a3 += v7 * bf2f(m7.w);
    }
    for (; e + 2 <= e1; e += 2) {
        int   s0 = csr_src[e+0], s1 = csr_src[e+1];
        float v0 = csr_val[e+0], v1 = csr_val[e+1];
        ushort4 m0 = *(const ushort4*)(Hf + (size_t)s0 * FOUT);
        ushort4 m1 = *(const ushort4*)(Hf + (size_t)s1 * FOUT);
        a0 += v0 * bf2f(m0.x); a1 += v0 * bf2f(m0.y); a2 += v0 * bf2f(m0.z); a3 += v0 * bf2f(m0.w);
        a0 += v1 * bf2f(m1.x); a1 += v1 * bf2f(m1.y); a2 += v1 * bf2f(m1.z); a3 += v1 * bf2f(m1.w);
    }
    if (e < e1) {
        int   s0 = csr_src[e];
        float v0 = csr_val[e];
        ushort4 m0 = *(const ushort4*)(Hf + (size_t)s0 * FOUT);
        a0 += v0 * bf2f(m0.x); a1 += v0 * bf2f(m0.y); a2 += v0 * bf2f(m0.z); a3 += v0 * bf2f(m0.w);
    }

    float4 bv = *(const float4*)(bias + 4 * f4);
    a0 += bv.x; a1 += bv.y; a2 += bv.z; a3 += bv.w;
    if (RELU) {
        a0 = fmaxf(a0, 0.f); a1 = fmaxf(a1, 0.f);
        a2 = fmaxf(a2, 0.f); a3 = fmaxf(a3, 0.f);
    }
    if (OBF16) {
        ushort4 o = make_ushort4(f2bf(a0), f2bf(a1), f2bf(a2), f2bf(a3));
        *(ushort4*)((ushort_t*)outv + (size_t)node * FOUT + 4 * f4) = o;
    } else {
        *(float4*)((float*)outv + (size_t)node * FOUT + 4 * f4) = make_float4(a0, a1, a2, a3);
    }
}

// ---------------- launch ----------------

extern "C" void kernel_launch(void* const* d_in, const int* in_sizes, int n_in,
                              void* d_out, int out_size, void* d_ws, size_t ws_size,
                              hipStream_t stream) {
    const float* x    = (const float*)d_in[0];
    const int*   eidx = (const int*)d_in[1];
    const float* ea   = (const float*)d_in[2];
    const float* W1   = (const float*)d_in[3];
    const float* b1   = (const float*)d_in[4];
    const float* W2   = (const float*)d_in[5];
    const float* b2   = (const float*)d_in[6];
    const float* W3   = (const float*)d_in[7];
    const float* b3   = (const float*)d_in[8];

    const int N = in_sizes[0] / 128;
    const int E = in_sizes[2];

    const int nbins = (N + 255) >> BIN_SHIFT;            // 196 for N=50000 (<=256)

    char*  base = (char*)d_ws;
    size_t off  = 0;
    auto carve = [&](size_t nbytes) -> void* {
        void* p = base + off;
        off = (off + nbytes + 255) & ~(size_t)255;
        return p;
    };
    int*   gcnt      = (int*)  carve((size_t)nbins * 4);
    uint2* binned    = (uint2*)carve((size_t)nbins * BCAP * 8);
    float* dinv      = (float*)carve((size_t)N * 4);
    int*   rowbeg    = (int*)  carve((size_t)N * 4);
    int*   rcnt      = (int*)  carve((size_t)N * 4);
    int*   csr_src   = (int*)  carve((size_t)nbins * BCAP * 4);
    float* csr_val   = (float*)carve((size_t)nbins * BCAP * 4);
    ushort_t* bufA   = (ushort_t*)carve((size_t)N * 128 * 2);   // bf16: gemm outputs H'
    ushort_t* bufB   = (ushort_t*)carve((size_t)N * 128 * 2);   // bf16: agg outputs G
    ushort_t* Wt1    = (ushort_t*)carve((size_t)128 * 128 * 2);
    ushort_t* Wt2    = (ushort_t*)carve((size_t)64 * 128 * 2);
    ushort_t* Wt3    = (ushort_t*)carve((size_t)32 * 64 * 2);
    (void)ws_size;

    const int wtot = 128 * 128 + 128 * 64 + 64 * 32;
    const int gScat = NBS + (wtot + 255) / 256;          // 64 scatter + 104 wconv blocks
    const int gR = (N + 127) / 128;                      // MFMA gemm blocks (128 rows/block)

    // preprocessing: memset counters, scatter+wconv, fused finish (3 dispatches)
    hipMemsetAsync(gcnt, 0, (size_t)nbins * 4, stream);
    k_scatter<<<gScat, BLK, 0, stream>>>(eidx, ea, gcnt, binned, nbins, E,
                                         W1, Wt1, W2, Wt2, W3, Wt3);
    k_bin_finish<<<nbins, BLK, 0, stream>>>(binned, gcnt, dinv, rowbeg, rcnt,
                                            csr_src, csr_val, N);

    // layer 1: 128 -> 128, relu  (gemm reads f32 x directly)
    k_gemm_mfma<128, 128, true><<<gR, BLK, 0, stream>>>(x, Wt1, dinv, bufA, N);
    k_agg<128, true, true><<<(N + 7) / 8, BLK, 0, stream>>>(bufA, dinv, rowbeg, rcnt, csr_src, csr_val, b1, bufB, N);

    // layer 2: 128 -> 64, relu
    k_gemm_mfma<128, 64, false><<<gR, BLK, 0, stream>>>(bufB, Wt2, dinv, bufA, N);
    k_agg<64, true, true><<<(N + 15) / 16, BLK, 0, stream>>>(bufA, dinv, rowbeg, rcnt, csr_src, csr_val, b2, bufB, N);

    // layer 3: 64 -> 32, no relu
    k_gemm_mfma<64, 32, false><<<gR, BLK, 0, stream>>>(bufB, Wt3, dinv, bufA, N);
    k_agg<32, false, false><<<(N + 31) / 32, BLK, 0, stream>>>(bufA, dinv, rowbeg, rcnt, csr_src, csr_val, b3, d_out, N);
}

// Round 15
// 142.630 us; speedup vs baseline: 1.1990x; 1.1990x over previous
//
#include <hip/hip_runtime.h>
#include <hip/hip_bf16.h>

#define BLK 256
#define SCAT_NB 512        // blocks in the binning scatter pass
#define BIN_SHIFT 8        // 256 nodes per bin
#define STAGE_CAP 6144     // LDS-staged edges per bin (mean ~4080, 19-sigma headroom)

typedef unsigned short ushort_t;
typedef unsigned int uint_t;
typedef unsigned long long ull_t;
typedef __attribute__((ext_vector_type(8))) short bf16x8;
typedef __attribute__((ext_vector_type(4))) float f32x4;

static __device__ __forceinline__ float bf2f(ushort_t u) {
    return __uint_as_float((uint_t)u << 16);
}
static __device__ __forceinline__ ushort_t f2bf(float f) {
    __hip_bfloat16 h = __float2bfloat16(f);   // RNE
    return *reinterpret_cast<ushort_t*>(&h);
}

// ================= R14 post-mortem =================
// Fixed-capacity bins + 64-block bulk reservation (R13->R14 attempt) regressed
// 141->171us: 64 scatter blocks = 2.6% occupancy (latency-bound), and raising
// blocks to 512 would make 512-long serialized atomic reservation chains.
// REVERTED to the scan-based build (R13, 141.5us): its 3 extra dispatches cost
// ~6us total and keep 512-block parallelism with zero global atomics.
// Normalization stays factorized (R12): H' = dinv*(G@W), csr_val = w*dinv[d].

// ---------------- fused prologue: bin_count + weight conv ----------------

__global__ __launch_bounds__(256) void k_pre(const int* __restrict__ eidx,
                                             int* __restrict__ bcnt,
                                             int nbins, int epb, int E,
                                             const float* __restrict__ W1, ushort_t* __restrict__ Wt1,
                                             const float* __restrict__ W2, ushort_t* __restrict__ Wt2,
                                             const float* __restrict__ W3, ushort_t* __restrict__ Wt3) {
    const int b = blockIdx.x;
    const int t = threadIdx.x;
    if (b < SCAT_NB) {
        __shared__ int h[256];
        h[t] = 0;
        __syncthreads();
        const int base = b * epb;
        const int lim  = min(base + epb, E);
        for (int e = base + t; e < lim; e += 256)
            atomicAdd(&h[eidx[E + e] >> BIN_SHIFT], 1);
        __syncthreads();
        if (t < nbins) bcnt[(size_t)t * SCAT_NB + b] = h[t];
    } else {
        int j = (b - SCAT_NB) * 256 + t;   // W[fin][fout] -> Wt[fout][fin] bf16
        if (j < 128 * 128) {
            int r = j / 128, c = j % 128;
            Wt1[(size_t)c * 128 + r] = f2bf(W1[j]);
        } else if (j < 128 * 128 + 128 * 64) {
            j -= 128 * 128;
            int r = j / 64, c = j % 64;
            Wt2[(size_t)c * 128 + r] = f2bf(W2[j]);
        } else if (j < 128 * 128 + 128 * 64 + 64 * 32) {
            j -= 128 * 128 + 128 * 64;
            int r = j / 32, c = j % 32;
            Wt3[(size_t)c * 64 + r] = f2bf(W3[j]);
        }
    }
}

// ---------------- scans for the bin-offset table ----------------

__global__ __launch_bounds__(256) void k_scan1(const int* __restrict__ cnt,
                                               int* rowptr, int* bsum, int n) {
    __shared__ int tile[256];
    const int t = threadIdx.x;
    const int i = blockIdx.x * 256 + t;
    int v = (i < n) ? cnt[i] : 0;
    tile[t] = v;
    __syncthreads();
    for (int off = 1; off < 256; off <<= 1) {
        int x = (t >= off) ? tile[t - off] : 0;
        __syncthreads();
        tile[t] += x;
        __syncthreads();
    }
    if (i < n) rowptr[i] = tile[t] - v;
    if (t == 255) bsum[blockIdx.x] = tile[255];
}

// single block, arbitrary n (serial tiles with carry), in-place exclusive
__global__ __launch_bounds__(256) void k_scan2x(int* a, int n) {
    __shared__ int tile[256];
    __shared__ int carry_s;
    const int t = threadIdx.x;
    if (t == 0) carry_s = 0;
    __syncthreads();
    for (int base = 0; base < n; base += 256) {
        int i = base + t;
        int v = (i < n) ? a[i] : 0;
        tile[t] = v;
        __syncthreads();
        for (int off = 1; off < 256; off <<= 1) {
            int x = (t >= off) ? tile[t - off] : 0;
            __syncthreads();
            tile[t] += x;
            __syncthreads();
        }
        int carry = carry_s;
        if (i < n) a[i] = carry + tile[t] - v;
        __syncthreads();
        if (t == 255) carry_s = carry + tile[255];
        __syncthreads();
    }
}

// consumers reconstruct global offsets as ebofs[idx] + bsumB[idx>>8]

// ---------------- binned edge scatter (8B packed: (s<<8)|(d&255), w) ----------------

__global__ __launch_bounds__(256) void k_bin_scatter(const int* __restrict__ eidx,
                                                     const float* __restrict__ ea,
                                                     const int* __restrict__ ebofs,
                                                     const int* __restrict__ bsumB,
                                                     uint2* __restrict__ binned,
                                                     int nbins, int epb, int E) {
    __shared__ int h[256];
    __shared__ int lofs[256];
    const int t = threadIdx.x;
    h[t] = 0;
    if (t < nbins) {
        int idx = t * SCAT_NB + blockIdx.x;
        lofs[t] = ebofs[idx] + bsumB[idx >> 8];
    }
    __syncthreads();
    const int base = blockIdx.x * epb;
    const int lim  = min(base + epb, E);
    for (int e = base + t; e < lim; e += 256) {
        int s = eidx[e];
        int d = eidx[E + e];
        float w = ea[e];
        int bin = d >> BIN_SHIFT;
        int r = atomicAdd(&h[bin], 1);      // LDS-local rank
        int pos = lofs[bin] + r;
        binned[pos] = make_uint2(((uint_t)s << 8) | (uint_t)(d & 255), __float_as_uint(w));
    }
}

// ---------------- fused per-bin hist + rowptr + dinv + CSR emit ----------------
// Stages the bin's packed edges in LDS (one global read), u64 packed hist
// (cnt | fixed-point weighted deg), LDS scan -> rowptr, then emits csr from LDS.
// csr_val = w * dinv[d] (dinv[s] folded into H' by the GEMM epilogue).

__global__ __launch_bounds__(256) void k_bin_finish(const uint2* __restrict__ binned,
                                                    const int* __restrict__ ebofs,
                                                    const int* __restrict__ bsumB,
                                                    float* __restrict__ dinv,
                                                    int* __restrict__ rowptr,
                                                    int* __restrict__ csr_src,
                                                    float* __restrict__ csr_val,
                                                    int nbins, int N, int E) {
    __shared__ uint2 stage[STAGE_CAP];   // 48 KB
    __shared__ ull_t hs[256];
    __shared__ int   sc[256];
    __shared__ int   rp[256];
    __shared__ float dl[256];
    __shared__ int   c2[256];
    const int t = threadIdx.x;
    const int b = blockIdx.x;
    hs[t] = 0ull;
    c2[t] = 0;
    __syncthreads();
    const int i0 = b * SCAT_NB;
    const int start = ebofs[i0] + bsumB[i0 >> 8];
    int end = E;
    if (b + 1 < nbins) {
        int i1 = (b + 1) * SCAT_NB;
        end = ebofs[i1] + bsumB[i1 >> 8];
    }
    const int cnt = end - start;
    const bool fits = (cnt <= STAGE_CAP);

    // phase 1: histogram (+ LDS staging when it fits)
    if (fits) {
        for (int i = t; i < cnt; i += 256) {
            uint2 p = binned[start + i];
            stage[i] = p;
            atomicAdd(&hs[p.x & 255],
                      (1ull << 40) | (ull_t)(__uint_as_float(p.y) * 4294967296.0f));
        }
    } else {
        for (int i = start + t; i < end; i += 256) {
            uint2 p = binned[i];
            atomicAdd(&hs[p.x & 255],
                      (1ull << 40) | (ull_t)(__uint_as_float(p.y) * 4294967296.0f));
        }
    }
    __syncthreads();

    // scan counts -> per-node exclusive offsets; compute dinv
    int v = (int)(hs[t] >> 40);
    sc[t] = v;
    __syncthreads();
    for (int off = 1; off < 256; off <<= 1) {
        int x = (t >= off) ? sc[t - off] : 0;
        __syncthreads();
        sc[t] += x;
        __syncthreads();
    }
    {
        ull_t s = hs[t];
        float dg = 1.0f + (float)(s & ((1ull << 40) - 1)) * (1.0f / 4294967296.0f);
        float di = rsqrtf(dg);
        dl[t] = di;
        rp[t] = start + sc[t] - v;
        const int node = (b << BIN_SHIFT) + t;
        if (node < N) {
            dinv[node]   = di;
            rowptr[node] = rp[t];
        }
        if (b == 0 && t == 0) rowptr[N] = E;
    }
    __syncthreads();

    // phase 2: emit
    if (fits) {
        for (int i = t; i < cnt; i += 256) {
            uint2 p = stage[i];
            int d8 = p.x & 255;
            int r = atomicAdd(&c2[d8], 1);
            int pos = rp[d8] + r;
            csr_src[pos] = (int)(p.x >> 8);
            csr_val[pos] = __uint_as_float(p.y) * dl[d8];
        }
    } else {
        for (int i = start + t; i < end; i += 256) {
            uint2 p = binned[i];
            int d8 = p.x & 255;
            int r = atomicAdd(&c2[d8], 1);
            int pos = rp[d8] + r;
            csr_src[pos] = (int)(p.x >> 8);
            csr_val[pos] = __uint_as_float(p.y) * dl[d8];
        }
    }
}

// ---------------- MFMA GEMM: C[n,FOUT](bf16) = dinv * (A[n,FIN] @ Wt^T) ----------------
// 32 rows/wave; mfma_f32_16x16x32_bf16; A-frag row=lane&15 k=(lane>>4)*8+j;
// B-frag col=lane&15; C/D col=lane&15 row=(lane>>4)*4+reg (m89-verified).
// AF32: layer 1 reads f32 x directly (in-register bf16 cvt) - kills the cvt pass.
// Epilogue scales each output row by dinv[row] (normalization factorization).

template <int FIN, int FOUT, bool AF32>
__global__ __launch_bounds__(256) void k_gemm_mfma(const void* __restrict__ Av,
                                                   const ushort_t* __restrict__ Wt,
                                                   const float* __restrict__ dinv,
                                                   ushort_t* __restrict__ C, int n) {
    constexpr int NT = FOUT / 16;      // col tiles
    constexpr int NK = FIN / 32;       // K steps
    const int wave = threadIdx.x >> 6;
    const int lane = threadIdx.x & 63;
    const int r0 = (blockIdx.x * 4 + wave) * 32;
    if (r0 >= n) return;

    const int l15 = lane & 15;
    const int kg  = lane >> 4;
    const int arow0 = min(r0 + l15, n - 1);        // tail clamp; bad rows never stored
    const int arow1 = min(r0 + 16 + l15, n - 1);

    f32x4 acc0[NT], acc1[NT];
#pragma unroll
    for (int c = 0; c < NT; ++c) { acc0[c] = (f32x4)(0.0f); acc1[c] = (f32x4)(0.0f); }

    const ushort_t* Bp = Wt + (size_t)l15 * FIN + kg * 8;

#pragma unroll 1   // keep rolled: full unroll hoists all B loads -> spill (R1 lesson)
    for (int ks = 0; ks < NK; ++ks) {
        bf16x8 a0, a1;
        if (AF32) {
            const float* A = (const float*)Av;
            const float* p0 = A + (size_t)arow0 * FIN + kg * 8 + ks * 32;
            const float* p1 = A + (size_t)arow1 * FIN + kg * 8 + ks * 32;
            float4 u0 = *(const float4*)p0, u1 = *(const float4*)(p0 + 4);
            float4 w0 = *(const float4*)p1, w1 = *(const float4*)(p1 + 4);
            a0[0] = (short)f2bf(u0.x); a0[1] = (short)f2bf(u0.y);
            a0[2] = (short)f2bf(u0.z); a0[3] = (short)f2bf(u0.w);
            a0[4] = (short)f2bf(u1.x); a0[5] = (short)f2bf(u1.y);
            a0[6] = (short)f2bf(u1.z); a0[7] = (short)f2bf(u1.w);
            a1[0] = (short)f2bf(w0.x); a1[1] = (short)f2bf(w0.y);
            a1[2] = (short)f2bf(w0.z); a1[3] = (short)f2bf(w0.w);
            a1[4] = (short)f2bf(w1.x); a1[5] = (short)f2bf(w1.y);
            a1[6] = (short)f2bf(w1.z); a1[7] = (short)f2bf(w1.w);
        } else {
            const ushort_t* A = (const ushort_t*)Av;
            a0 = *(const bf16x8*)(A + (size_t)arow0 * FIN + kg * 8 + ks * 32);
            a1 = *(const bf16x8*)(A + (size_t)arow1 * FIN + kg * 8 + ks * 32);
        }
#pragma unroll
        for (int c = 0; c < NT; ++c) {
            bf16x8 bfr = *(const bf16x8*)(Bp + (size_t)c * 16 * FIN + ks * 32);
            acc0[c] = __builtin_amdgcn_mfma_f32_16x16x32_bf16(a0, bfr, acc0[c], 0, 0, 0);
            acc1[c] = __builtin_amdgcn_mfma_f32_16x16x32_bf16(a1, bfr, acc1[c], 0, 0, 0);
        }
    }

#pragma unroll
    for (int g = 0; g < 2; ++g) {
        const int rbase = r0 + g * 16 + kg * 4;
#pragma unroll
        for (int j = 0; j < 4; ++j) {
            int row = rbase + j;
            if (row < n) {
                float dscale = dinv[row];
#pragma unroll
                for (int c = 0; c < NT; ++c) {
                    float val = (g == 0) ? acc0[c][j] : acc1[c][j];
                    C[(size_t)row * FOUT + c * 16 + l15] = f2bf(val * dscale);
                }
            }
        }
    }
}

// ---------------- aggregation (bf16 H', ushort4 gathers, x8-unrolled) ----------------
// out = dinv[node]*H'[node] + sum_e csr_val*H'[src] + b  (H' has dinv folded in)

template <int FOUT, bool RELU, bool OBF16>
__global__ __launch_bounds__(256) void k_agg(const ushort_t* __restrict__ H,
                                             const float* __restrict__ dinv,
                                             const int* __restrict__ rowptr,
                                             const int* __restrict__ csr_src,
                                             const float* __restrict__ csr_val,
                                             const float* __restrict__ bias,
                                             void* __restrict__ outv, int n) {
    constexpr int LPN = FOUT / 4;          // lanes per node: 32 / 16 / 8
    constexpr int NPW = 64 / LPN;          // nodes per wave: 2 / 4 / 8
    const int wave = threadIdx.x >> 6;
    const int lane = threadIdx.x & 63;
    const int sub  = lane / LPN;
    const int f4   = lane % LPN;           // feature-quad index
    const int node = (blockIdx.x * 4 + wave) * NPW + sub;
    if (node >= n) return;

    const ushort_t* __restrict__ Hf = H + 4 * f4;   // lane-fixed column base

    const float sn = dinv[node];
    ushort4 hv = *(const ushort4*)(Hf + (size_t)node * FOUT);
    float a0 = sn * bf2f(hv.x);
    float a1 = sn * bf2f(hv.y);
    float a2 = sn * bf2f(hv.z);
    float a3 = sn * bf2f(hv.w);

    const int e0 = rowptr[node], e1 = rowptr[node + 1];
    int e = e0;
    for (; e + 8 <= e1; e += 8) {
        int   s0 = csr_src[e+0], s1 = csr_src[e+1], s2 = csr_src[e+2], s3 = csr_src[e+3];
        int   s4 = csr_src[e+4], s5 = csr_src[e+5], s6 = csr_src[e+6], s7 = csr_src[e+7];
        float v0 = csr_val[e+0], v1 = csr_val[e+1], v2 = csr_val[e+2], v3 = csr_val[e+3];
        float v4 = csr_val[e+4], v5 = csr_val[e+5], v6 = csr_val[e+6], v7 = csr_val[e+7];
        ushort4 m0 = *(const ushort4*)(Hf + (size_t)s0 * FOUT);
        ushort4 m1 = *(const ushort4*)(Hf + (size_t)s1 * FOUT);
        ushort4 m2 = *(const ushort4*)(Hf + (size_t)s2 * FOUT);
        ushort4 m3 = *(const ushort4*)(Hf + (size_t)s3 * FOUT);
        ushort4 m4 = *(const ushort4*)(Hf + (size_t)s4 * FOUT);
        ushort4 m5 = *(const ushort4*)(Hf + (size_t)s5 * FOUT);
        ushort4 m6 = *(const ushort4*)(Hf + (size_t)s6 * FOUT);
        ushort4 m7 = *(const ushort4*)(Hf + (size_t)s7 * FOUT);
        a0 += v0 * bf2f(m0.x); a1 += v0 * bf2f(m0.y); a2 += v0 * bf2f(m0.z); a3 += v0 * bf2f(m0.w);
        a0 += v1 * bf2f(m1.x); a1 += v1 * bf2f(m1.y); a2 += v1 * bf2f(m1.z); a3 += v1 * bf2f(m1.w);
        a0 += v2 * bf2f(m2.x); a1 += v2 * bf2f(m2.y); a2 += v2 * bf2f(m2.z); a3 += v2 * bf2f(m2.w);
        a0 += v3 * bf2f(m3.x); a1 += v3 * bf2f(m3.y); a2 += v3 * bf2f(m3.z); a3 += v3 * bf2f(m3.w);
        a0 += v4 * bf2f(m4.x); a1 += v4 * bf2f(m4.y); a2 += v4 * bf2f(m4.z); a3 += v4 * bf2f(m4.w);
        a0 += v5 * bf2f(m5.x); a1 += v5 * bf2f(m5.y); a2 += v5 * bf2f(m5.z); a3 += v5 * bf2f(m5.w);
        a0 += v6 * bf2f(m6.x); a1 += v6 * bf2f(m6.y); a2 += v6 * bf2f(m6.z); a3 += v6 * bf2f(m6.w);
        a0 += v7 * bf2f(m7.x); a1 += v7 * bf2f(m7.y); a2 += v7 * bf2f(m7.z); a3 += v7 * bf2f(m7.w);
    }
    for (; e + 2 <= e1; e += 2) {
        int   s0 = csr_src[e+0], s1 = csr_src[e+1];
        float v0 = csr_val[e+0], v1 = csr_val[e+1];
        ushort4 m0 = *(const ushort4*)(Hf + (size_t)s0 * FOUT);
        ushort4 m1 = *(const ushort4*)(Hf + (size_t)s1 * FOUT);
        a0 += v0 * bf2f(m0.x); a1 += v0 * bf2f(m0.y); a2 += v0 * bf2f(m0.z); a3 += v0 * bf2f(m0.w);
        a0 += v1 * bf2f(m1.x); a1 += v1 * bf2f(m1.y); a2 += v1 * bf2f(m1.z); a3 += v1 * bf2f(m1.w);
    }
    if (e < e1) {
        int   s0 = csr_src[e];
        float v0 = csr_val[e];
        ushort4 m0 = *(const ushort4*)(Hf + (size_t)s0 * FOUT);
        a0 += v0 * bf2f(m0.x); a1 += v0 * bf2f(m0.y); a2 += v0 * bf2f(m0.z); a3 += v0 * bf2f(m0.w);
    }

    float4 bv = *(const float4*)(bias + 4 * f4);
    a0 += bv.x; a1 += bv.y; a2 += bv.z; a3 += bv.w;
    if (RELU) {
        a0 = fmaxf(a0, 0.f); a1 = fmaxf(a1, 0.f);
        a2 = fmaxf(a2, 0.f); a3 = fmaxf(a3, 0.f);
    }
    if (OBF16) {
        ushort4 o = make_ushort4(f2bf(a0), f2bf(a1), f2bf(a2), f2bf(a3));
        *(ushort4*)((ushort_t*)outv + (size_t)node * FOUT + 4 * f4) = o;
    } else {
        *(float4*)((float*)outv + (size_t)node * FOUT + 4 * f4) = make_float4(a0, a1, a2, a3);
    }
}

// ---------------- launch ----------------

extern "C" void kernel_launch(void* const* d_in, const int* in_sizes, int n_in,
                              void* d_out, int out_size, void* d_ws, size_t ws_size,
                              hipStream_t stream) {
    const float* x    = (const float*)d_in[0];
    const int*   eidx = (const int*)d_in[1];
    const float* ea   = (const float*)d_in[2];
    const float* W1   = (const float*)d_in[3];
    const float* b1   = (const float*)d_in[4];
    const float* W2   = (const float*)d_in[5];
    const float* b2   = (const float*)d_in[6];
    const float* W3   = (const float*)d_in[7];
    const float* b3   = (const float*)d_in[8];

    const int N = in_sizes[0] / 128;
    const int E = in_sizes[2];

    const int nbins = (N + 255) >> BIN_SHIFT;            // 196 for N=50000 (<=256)
    const int epb   = (E + SCAT_NB - 1) / SCAT_NB;       // edges per scatter block
    const int nbc   = nbins * SCAT_NB;                   // bcnt/ebofs length
    const int gBC   = (nbc + BLK - 1) / BLK;

    char*  base = (char*)d_ws;
    size_t off  = 0;
    auto carve = [&](size_t nbytes) -> void* {
        void* p = base + off;
        off = (off + nbytes + 255) & ~(size_t)255;
        return p;
    };
    int*   bcnt      = (int*)  carve((size_t)nbc * 4);
    int*   ebofs     = (int*)  carve((size_t)nbc * 4);
    int*   bsumB     = (int*)  carve((size_t)512 * 4);
    uint2* binned    = (uint2*)carve((size_t)E * 8);
    float* dinv      = (float*)carve((size_t)N * 4);
    int*   rowptr    = (int*)  carve((size_t)(N + 1) * 4);
    int*   csr_src   = (int*)  carve((size_t)E * 4);
    float* csr_val   = (float*)carve((size_t)E * 4);
    ushort_t* bufA   = (ushort_t*)carve((size_t)N * 128 * 2);   // bf16: gemm outputs H'
    ushort_t* bufB   = (ushort_t*)carve((size_t)N * 128 * 2);   // bf16: agg outputs G
    ushort_t* Wt1    = (ushort_t*)carve((size_t)128 * 128 * 2);
    ushort_t* Wt2    = (ushort_t*)carve((size_t)64 * 128 * 2);
    ushort_t* Wt3    = (ushort_t*)carve((size_t)32 * 64 * 2);
    (void)ws_size;

    const int wtot = 128 * 128 + 128 * 64 + 64 * 32;
    const int gPre = SCAT_NB + (wtot + 255) / 256;
    const int gR = (N + 127) / 128;                      // MFMA gemm blocks (128 rows/block)

    // prologue: bin_count + weight transpose/convert (one dispatch; x stays f32)
    k_pre<<<gPre, BLK, 0, stream>>>(eidx, bcnt, nbins, epb, E, W1, Wt1, W2, Wt2, W3, Wt3);
    // scan bin offsets (global offsets reconstructed inline by consumers)
    k_scan1<<<gBC, BLK, 0, stream>>>(bcnt, ebofs, bsumB, nbc);
    k_scan2x<<<1, BLK, 0, stream>>>(bsumB, gBC);
    // binned CSR build (no global atomics): scatter, then fused hist+rowptr+dinv+emit
    k_bin_scatter<<<SCAT_NB, BLK, 0, stream>>>(eidx, ea, ebofs, bsumB, binned, nbins, epb, E);
    k_bin_finish<<<nbins, BLK, 0, stream>>>(binned, ebofs, bsumB, dinv, rowptr,
                                            csr_src, csr_val, nbins, N, E);

    // layer 1: 128 -> 128, relu  (gemm reads f32 x directly)
    k_gemm_mfma<128, 128, true><<<gR, BLK, 0, stream>>>(x, Wt1, dinv, bufA, N);
    k_agg<128, true, true><<<(N + 7) / 8, BLK, 0, stream>>>(bufA, dinv, rowptr, csr_src, csr_val, b1, bufB, N);

    // layer 2: 128 -> 64, relu
    k_gemm_mfma<128, 64, false><<<gR, BLK, 0, stream>>>(bufB, Wt2, dinv, bufA, N);
    k_agg<64, true, true><<<(N + 15) / 16, BLK, 0, stream>>>(bufA, dinv, rowptr, csr_src, csr_val, b2, bufB, N);

    // layer 3: 64 -> 32, no relu
    k_gemm_mfma<64, 32, false><<<gR, BLK, 0, stream>>>(bufB, Wt3, dinv, bufA, N);
    k_agg<32, false, false><<<(N + 31) / 32, BLK, 0, stream>>>(bufA, dinv, rowptr, csr_src, csr_val, b3, d_out, N);
}

// Round 16
// 136.796 us; speedup vs baseline: 1.2501x; 1.0426x over previous
//
#include <hip/hip_runtime.h>
#include <hip/hip_bf16.h>

#define BLK 256
#define SCAT_NB 512        // blocks in the binning scatter pass
#define BIN_SHIFT 8        // 256 nodes per bin
#define STAGE_CAP 6144     // LDS-staged edges per bin (mean ~4080, 19-sigma headroom)

typedef unsigned short ushort_t;
typedef unsigned int uint_t;
typedef unsigned long long ull_t;
typedef __attribute__((ext_vector_type(8))) short bf16x8;
typedef __attribute__((ext_vector_type(4))) float f32x4;

static __device__ __forceinline__ float bf2f(ushort_t u) {
    return __uint_as_float((uint_t)u << 16);
}
static __device__ __forceinline__ ushort_t f2bf(float f) {
    __hip_bfloat16 h = __float2bfloat16(f);   // RNE
    return *reinterpret_cast<ushort_t*>(&h);
}

// ================= structure (R15) =================
// gemm_l -> agg_l needs a global barrier (gather reads ALL rows of H').
// agg_l -> gemm_{l+1} is row-local -> FUSED through LDS: one block aggregates
// 32 nodes into a [32][FIN] bf16 LDS tile, syncs, then MFMAs the tile against
// Wt from global. Saves 2 launches + 38MB of bufB round-trip traffic.
// Normalization stays factorized (R12): H' = dinv*(G@W), csr_val = w*dinv[d].

// ---------------- fused prologue: bin_count + weight conv ----------------

__global__ __launch_bounds__(256) void k_pre(const int* __restrict__ eidx,
                                             int* __restrict__ bcnt,
                                             int nbins, int epb, int E,
                                             const float* __restrict__ W1, ushort_t* __restrict__ Wt1,
                                             const float* __restrict__ W2, ushort_t* __restrict__ Wt2,
                                             const float* __restrict__ W3, ushort_t* __restrict__ Wt3) {
    const int b = blockIdx.x;
    const int t = threadIdx.x;
    if (b < SCAT_NB) {
        __shared__ int h[256];
        h[t] = 0;
        __syncthreads();
        const int base = b * epb;
        const int lim  = min(base + epb, E);
        for (int e = base + t; e < lim; e += 256)
            atomicAdd(&h[eidx[E + e] >> BIN_SHIFT], 1);
        __syncthreads();
        if (t < nbins) bcnt[(size_t)t * SCAT_NB + b] = h[t];
    } else {
        int j = (b - SCAT_NB) * 256 + t;   // W[fin][fout] -> Wt[fout][fin] bf16
        if (j < 128 * 128) {
            int r = j / 128, c = j % 128;
            Wt1[(size_t)c * 128 + r] = f2bf(W1[j]);
        } else if (j < 128 * 128 + 128 * 64) {
            j -= 128 * 128;
            int r = j / 64, c = j % 64;
            Wt2[(size_t)c * 128 + r] = f2bf(W2[j]);
        } else if (j < 128 * 128 + 128 * 64 + 64 * 32) {
            j -= 128 * 128 + 128 * 64;
            int r = j / 32, c = j % 32;
            Wt3[(size_t)c * 64 + r] = f2bf(W3[j]);
        }
    }
}

// ---------------- scans for the bin-offset table ----------------

__global__ __launch_bounds__(256) void k_scan1(const int* __restrict__ cnt,
                                               int* rowptr, int* bsum, int n) {
    __shared__ int tile[256];
    const int t = threadIdx.x;
    const int i = blockIdx.x * 256 + t;
    int v = (i < n) ? cnt[i] : 0;
    tile[t] = v;
    __syncthreads();
    for (int off = 1; off < 256; off <<= 1) {
        int x = (t >= off) ? tile[t - off] : 0;
        __syncthreads();
        tile[t] += x;
        __syncthreads();
    }
    if (i < n) rowptr[i] = tile[t] - v;
    if (t == 255) bsum[blockIdx.x] = tile[255];
}

// single block, arbitrary n (serial tiles with carry), in-place exclusive
__global__ __launch_bounds__(256) void k_scan2x(int* a, int n) {
    __shared__ int tile[256];
    __shared__ int carry_s;
    const int t = threadIdx.x;
    if (t == 0) carry_s = 0;
    __syncthreads();
    for (int base = 0; base < n; base += 256) {
        int i = base + t;
        int v = (i < n) ? a[i] : 0;
        tile[t] = v;
        __syncthreads();
        for (int off = 1; off < 256; off <<= 1) {
            int x = (t >= off) ? tile[t - off] : 0;
            __syncthreads();
            tile[t] += x;
            __syncthreads();
        }
        int carry = carry_s;
        if (i < n) a[i] = carry + tile[t] - v;
        __syncthreads();
        if (t == 255) carry_s = carry + tile[255];
        __syncthreads();
    }
}

// consumers reconstruct global offsets as ebofs[idx] + bsumB[idx>>8]

// ---------------- binned edge scatter (8B packed: (s<<8)|(d&255), w) ----------------

__global__ __launch_bounds__(256) void k_bin_scatter(const int* __restrict__ eidx,
                                                     const float* __restrict__ ea,
                                                     const int* __restrict__ ebofs,
                                                     const int* __restrict__ bsumB,
                                                     uint2* __restrict__ binned,
                                                     int nbins, int epb, int E) {
    __shared__ int h[256];
    __shared__ int lofs[256];
    const int t = threadIdx.x;
    h[t] = 0;
    if (t < nbins) {
        int idx = t * SCAT_NB + blockIdx.x;
        lofs[t] = ebofs[idx] + bsumB[idx >> 8];
    }
    __syncthreads();
    const int base = blockIdx.x * epb;
    const int lim  = min(base + epb, E);
    for (int e = base + t; e < lim; e += 256) {
        int s = eidx[e];
        int d = eidx[E + e];
        float w = ea[e];
        int bin = d >> BIN_SHIFT;
        int r = atomicAdd(&h[bin], 1);      // LDS-local rank
        int pos = lofs[bin] + r;
        binned[pos] = make_uint2(((uint_t)s << 8) | (uint_t)(d & 255), __float_as_uint(w));
    }
}

// ---------------- fused per-bin hist + rowptr + dinv + CSR emit ----------------

__global__ __launch_bounds__(256) void k_bin_finish(const uint2* __restrict__ binned,
                                                    const int* __restrict__ ebofs,
                                                    const int* __restrict__ bsumB,
                                                    float* __restrict__ dinv,
                                                    int* __restrict__ rowptr,
                                                    int* __restrict__ csr_src,
                                                    float* __restrict__ csr_val,
                                                    int nbins, int N, int E) {
    __shared__ uint2 stage[STAGE_CAP];   // 48 KB
    __shared__ ull_t hs[256];
    __shared__ int   sc[256];
    __shared__ int   rp[256];
    __shared__ float dl[256];
    __shared__ int   c2[256];
    const int t = threadIdx.x;
    const int b = blockIdx.x;
    hs[t] = 0ull;
    c2[t] = 0;
    __syncthreads();
    const int i0 = b * SCAT_NB;
    const int start = ebofs[i0] + bsumB[i0 >> 8];
    int end = E;
    if (b + 1 < nbins) {
        int i1 = (b + 1) * SCAT_NB;
        end = ebofs[i1] + bsumB[i1 >> 8];
    }
    const int cnt = end - start;
    const bool fits = (cnt <= STAGE_CAP);

    if (fits) {
        for (int i = t; i < cnt; i += 256) {
            uint2 p = binned[start + i];
            stage[i] = p;
            atomicAdd(&hs[p.x & 255],
                      (1ull << 40) | (ull_t)(__uint_as_float(p.y) * 4294967296.0f));
        }
    } else {
        for (int i = start + t; i < end; i += 256) {
            uint2 p = binned[i];
            atomicAdd(&hs[p.x & 255],
                      (1ull << 40) | (ull_t)(__uint_as_float(p.y) * 4294967296.0f));
        }
    }
    __syncthreads();

    int v = (int)(hs[t] >> 40);
    sc[t] = v;
    __syncthreads();
    for (int off = 1; off < 256; off <<= 1) {
        int x = (t >= off) ? sc[t - off] : 0;
        __syncthreads();
        sc[t] += x;
        __syncthreads();
    }
    {
        ull_t s = hs[t];
        float dg = 1.0f + (float)(s & ((1ull << 40) - 1)) * (1.0f / 4294967296.0f);
        float di = rsqrtf(dg);
        dl[t] = di;
        rp[t] = start + sc[t] - v;
        const int node = (b << BIN_SHIFT) + t;
        if (node < N) {
            dinv[node]   = di;
            rowptr[node] = rp[t];
        }
        if (b == 0 && t == 0) rowptr[N] = E;
    }
    __syncthreads();

    if (fits) {
        for (int i = t; i < cnt; i += 256) {
            uint2 p = stage[i];
            int d8 = p.x & 255;
            int r = atomicAdd(&c2[d8], 1);
            int pos = rp[d8] + r;
            csr_src[pos] = (int)(p.x >> 8);
            csr_val[pos] = __uint_as_float(p.y) * dl[d8];
        }
    } else {
        for (int i = start + t; i < end; i += 256) {
            uint2 p = binned[i];
            int d8 = p.x & 255;
            int r = atomicAdd(&c2[d8], 1);
            int pos = rp[d8] + r;
            csr_src[pos] = (int)(p.x >> 8);
            csr_val[pos] = __uint_as_float(p.y) * dl[d8];
        }
    }
}

// ---------------- gather-accumulate body (shared by agg kernels) ----------------

template <int FIN>
static __device__ __forceinline__ void agg_body(const ushort_t* __restrict__ Hf,
                                                const int* __restrict__ csr_src,
                                                const float* __restrict__ csr_val,
                                                int e0, int e1,
                                                float& a0, float& a1, float& a2, float& a3) {
    int e = e0;
    for (; e + 8 <= e1; e += 8) {
        int   s0 = csr_src[e+0], s1 = csr_src[e+1], s2 = csr_src[e+2], s3 = csr_src[e+3];
        int   s4 = csr_src[e+4], s5 = csr_src[e+5], s6 = csr_src[e+6], s7 = csr_src[e+7];
        float v0 = csr_val[e+0], v1 = csr_val[e+1], v2 = csr_val[e+2], v3 = csr_val[e+3];
        float v4 = csr_val[e+4], v5 = csr_val[e+5], v6 = csr_val[e+6], v7 = csr_val[e+7];
        ushort4 m0 = *(const ushort4*)(Hf + (size_t)s0 * FIN);
        ushort4 m1 = *(const ushort4*)(Hf + (size_t)s1 * FIN);
        ushort4 m2 = *(const ushort4*)(Hf + (size_t)s2 * FIN);
        ushort4 m3 = *(const ushort4*)(Hf + (size_t)s3 * FIN);
        ushort4 m4 = *(const ushort4*)(Hf + (size_t)s4 * FIN);
        ushort4 m5 = *(const ushort4*)(Hf + (size_t)s5 * FIN);
        ushort4 m6 = *(const ushort4*)(Hf + (size_t)s6 * FIN);
        ushort4 m7 = *(const ushort4*)(Hf + (size_t)s7 * FIN);
        a0 += v0 * bf2f(m0.x); a1 += v0 * bf2f(m0.y); a2 += v0 * bf2f(m0.z); a3 += v0 * bf2f(m0.w);
        a0 += v1 * bf2f(m1.x); a1 += v1 * bf2f(m1.y); a2 += v1 * bf2f(m1.z); a3 += v1 * bf2f(m1.w);
        a0 += v2 * bf2f(m2.x); a1 += v2 * bf2f(m2.y); a2 += v2 * bf2f(m2.z); a3 += v2 * bf2f(m2.w);
        a0 += v3 * bf2f(m3.x); a1 += v3 * bf2f(m3.y); a2 += v3 * bf2f(m3.z); a3 += v3 * bf2f(m3.w);
        a0 += v4 * bf2f(m4.x); a1 += v4 * bf2f(m4.y); a2 += v4 * bf2f(m4.z); a3 += v4 * bf2f(m4.w);
        a0 += v5 * bf2f(m5.x); a1 += v5 * bf2f(m5.y); a2 += v5 * bf2f(m5.z); a3 += v5 * bf2f(m5.w);
        a0 += v6 * bf2f(m6.x); a1 += v6 * bf2f(m6.y); a2 += v6 * bf2f(m6.z); a3 += v6 * bf2f(m6.w);
        a0 += v7 * bf2f(m7.x); a1 += v7 * bf2f(m7.y); a2 += v7 * bf2f(m7.z); a3 += v7 * bf2f(m7.w);
    }
    for (; e + 2 <= e1; e += 2) {
        int   s0 = csr_src[e+0], s1 = csr_src[e+1];
        float v0 = csr_val[e+0], v1 = csr_val[e+1];
        ushort4 m0 = *(const ushort4*)(Hf + (size_t)s0 * FIN);
        ushort4 m1 = *(const ushort4*)(Hf + (size_t)s1 * FIN);
        a0 += v0 * bf2f(m0.x); a1 += v0 * bf2f(m0.y); a2 += v0 * bf2f(m0.z); a3 += v0 * bf2f(m0.w);
        a0 += v1 * bf2f(m1.x); a1 += v1 * bf2f(m1.y); a2 += v1 * bf2f(m1.z); a3 += v1 * bf2f(m1.w);
    }
    if (e < e1) {
        int   s0 = csr_src[e];
        float v0 = csr_val[e];
        ushort4 m0 = *(const ushort4*)(Hf + (size_t)s0 * FIN);
        a0 += v0 * bf2f(m0.x); a1 += v0 * bf2f(m0.y); a2 += v0 * bf2f(m0.z); a3 += v0 * bf2f(m0.w);
    }
}

// ---------------- FUSED agg + gemm: G = relu(agg(H')+b); C = dinv*(G @ Wt^T) ----------------
// Phase A: block aggregates 32 nodes (bias+relu) -> bf16 LDS tile [32][FIN+8].
// Phase B: 4 waves MFMA the tile vs Wt (A-frag from LDS, 2-way bank alias = free),
// epilogue row-scales by dinv. Saves the bufB global round-trip + a launch.

template <int FIN, int FOUT>
__global__ __launch_bounds__(256) void k_agg_gemm(const ushort_t* __restrict__ H,
                                                  const float* __restrict__ dinv,
                                                  const int* __restrict__ rowptr,
                                                  const int* __restrict__ csr_src,
                                                  const float* __restrict__ csr_val,
                                                  const float* __restrict__ bias,
                                                  const ushort_t* __restrict__ Wt,
                                                  ushort_t* __restrict__ C, int n) {
    constexpr int PAD = 8;
    __shared__ ushort_t Gs[32][FIN + PAD];
    constexpr int LPN = FIN / 4;       // lanes per node: 32 / 16
    constexpr int NPW = 64 / LPN;      // nodes per wave: 2 / 4
    constexpr int NPB = NPW * 4;       // nodes per block pass: 8 / 16
    constexpr int NPASS = 32 / NPB;    // 4 / 2
    constexpr int NT = FOUT / 16;      // col tiles: 4 / 2
    constexpr int NK = FIN / 32;       // K steps: 4 / 2

    const int wave = threadIdx.x >> 6;
    const int lane = threadIdx.x & 63;
    const int r0 = blockIdx.x * 32;
    const int sub = lane / LPN;
    const int f4  = lane % LPN;
    const ushort_t* __restrict__ Hf = H + 4 * f4;

    // ---- phase A: aggregate 32 nodes into LDS ----
#pragma unroll
    for (int p = 0; p < NPASS; ++p) {
        const int nb = p * NPB + wave * NPW + sub;
        const int node = r0 + nb;
        float a0 = 0.f, a1 = 0.f, a2 = 0.f, a3 = 0.f;
        if (node < n) {
            const float sn = dinv[node];
            ushort4 hv = *(const ushort4*)(Hf + (size_t)node * FIN);
            a0 = sn * bf2f(hv.x); a1 = sn * bf2f(hv.y);
            a2 = sn * bf2f(hv.z); a3 = sn * bf2f(hv.w);
            agg_body<FIN>(Hf, csr_src, csr_val, rowptr[node], rowptr[node + 1], a0, a1, a2, a3);
            float4 bv = *(const float4*)(bias + 4 * f4);
            a0 = fmaxf(a0 + bv.x, 0.f); a1 = fmaxf(a1 + bv.y, 0.f);
            a2 = fmaxf(a2 + bv.z, 0.f); a3 = fmaxf(a3 + bv.w, 0.f);
        }
        *(ushort4*)(&Gs[nb][4 * f4]) = make_ushort4(f2bf(a0), f2bf(a1), f2bf(a2), f2bf(a3));
    }
    __syncthreads();

    // ---- phase B: 32-row MFMA from LDS ----
    const int l15 = lane & 15;
    const int kg  = lane >> 4;
    for (int item = wave; item < 2 * NT; item += 4) {
        const int g  = item / NT;      // row group
        const int ct = item % NT;      // col tile
        f32x4 acc = (f32x4)(0.0f);
        const ushort_t* Bp = Wt + (size_t)(ct * 16 + l15) * FIN + kg * 8;
        const int arow = g * 16 + l15;
#pragma unroll
        for (int ks = 0; ks < NK; ++ks) {
            bf16x8 a = *(const bf16x8*)(&Gs[arow][kg * 8 + ks * 32]);
            bf16x8 b = *(const bf16x8*)(Bp + ks * 32);
            acc = __builtin_amdgcn_mfma_f32_16x16x32_bf16(a, b, acc, 0, 0, 0);
        }
        const int rbase = r0 + g * 16 + kg * 4;
#pragma unroll
        for (int j = 0; j < 4; ++j) {
            int row = rbase + j;
            if (row < n)
                C[(size_t)row * FOUT + ct * 16 + l15] = f2bf(acc[j] * dinv[row]);
        }
    }
}

// ---------------- MFMA GEMM (layer 1): C = dinv * (x(f32) @ Wt^T) ----------------

template <int FIN, int FOUT>
__global__ __launch_bounds__(256) void k_gemm_f32(const float* __restrict__ A,
                                                  const ushort_t* __restrict__ Wt,
                                                  const float* __restrict__ dinv,
                                                  ushort_t* __restrict__ C, int n) {
    constexpr int NT = FOUT / 16;
    constexpr int NK = FIN / 32;
    const int wave = threadIdx.x >> 6;
    const int lane = threadIdx.x & 63;
    const int r0 = (blockIdx.x * 4 + wave) * 32;
    if (r0 >= n) return;

    const int l15 = lane & 15;
    const int kg  = lane >> 4;
    const int arow0 = min(r0 + l15, n - 1);
    const int arow1 = min(r0 + 16 + l15, n - 1);

    f32x4 acc0[NT], acc1[NT];
#pragma unroll
    for (int c = 0; c < NT; ++c) { acc0[c] = (f32x4)(0.0f); acc1[c] = (f32x4)(0.0f); }

    const ushort_t* Bp = Wt + (size_t)l15 * FIN + kg * 8;

#pragma unroll 1   // keep rolled: full unroll hoists all B loads -> spill (R1 lesson)
    for (int ks = 0; ks < NK; ++ks) {
        bf16x8 a0, a1;
        const float* p0 = A + (size_t)arow0 * FIN + kg * 8 + ks * 32;
        const float* p1 = A + (size_t)arow1 * FIN + kg * 8 + ks * 32;
        float4 u0 = *(const float4*)p0, u1 = *(const float4*)(p0 + 4);
        float4 w0 = *(const float4*)p1, w1 = *(const float4*)(p1 + 4);
        a0[0] = (short)f2bf(u0.x); a0[1] = (short)f2bf(u0.y);
        a0[2] = (short)f2bf(u0.z); a0[3] = (short)f2bf(u0.w);
        a0[4] = (short)f2bf(u1.x); a0[5] = (short)f2bf(u1.y);
        a0[6] = (short)f2bf(u1.z); a0[7] = (short)f2bf(u1.w);
        a1[0] = (short)f2bf(w0.x); a1[1] = (short)f2bf(w0.y);
        a1[2] = (short)f2bf(w0.z); a1[3] = (short)f2bf(w0.w);
        a1[4] = (short)f2bf(w1.x); a1[5] = (short)f2bf(w1.y);
        a1[6] = (short)f2bf(w1.z); a1[7] = (short)f2bf(w1.w);
#pragma unroll
        for (int c = 0; c < NT; ++c) {
            bf16x8 bfr = *(const bf16x8*)(Bp + (size_t)c * 16 * FIN + ks * 32);
            acc0[c] = __builtin_amdgcn_mfma_f32_16x16x32_bf16(a0, bfr, acc0[c], 0, 0, 0);
            acc1[c] = __builtin_amdgcn_mfma_f32_16x16x32_bf16(a1, bfr, acc1[c], 0, 0, 0);
        }
    }

#pragma unroll
    for (int g = 0; g < 2; ++g) {
        const int rbase = r0 + g * 16 + kg * 4;
#pragma unroll
        for (int j = 0; j < 4; ++j) {
            int row = rbase + j;
            if (row < n) {
                float dscale = dinv[row];
#pragma unroll
                for (int c = 0; c < NT; ++c) {
                    float val = (g == 0) ? acc0[c][j] : acc1[c][j];
                    C[(size_t)row * FOUT + c * 16 + l15] = f2bf(val * dscale);
                }
            }
        }
    }
}

// ---------------- final aggregation (layer 3, f32 out, no relu) ----------------

template <int FIN>
__global__ __launch_bounds__(256) void k_agg_final(const ushort_t* __restrict__ H,
                                                   const float* __restrict__ dinv,
                                                   const int* __restrict__ rowptr,
                                                   const int* __restrict__ csr_src,
                                                   const float* __restrict__ csr_val,
                                                   const float* __restrict__ bias,
                                                   float* __restrict__ out, int n) {
    constexpr int LPN = FIN / 4;
    constexpr int NPW = 64 / LPN;
    const int wave = threadIdx.x >> 6;
    const int lane = threadIdx.x & 63;
    const int sub  = lane / LPN;
    const int f4   = lane % LPN;
    const int node = (blockIdx.x * 4 + wave) * NPW + sub;
    if (node >= n) return;

    const ushort_t* __restrict__ Hf = H + 4 * f4;
    const float sn = dinv[node];
    ushort4 hv = *(const ushort4*)(Hf + (size_t)node * FIN);
    float a0 = sn * bf2f(hv.x);
    float a1 = sn * bf2f(hv.y);
    float a2 = sn * bf2f(hv.z);
    float a3 = sn * bf2f(hv.w);

    agg_body<FIN>(Hf, csr_src, csr_val, rowptr[node], rowptr[node + 1], a0, a1, a2, a3);

    float4 bv = *(const float4*)(bias + 4 * f4);
    a0 += bv.x; a1 += bv.y; a2 += bv.z; a3 += bv.w;
    *(float4*)(out + (size_t)node * FIN + 4 * f4) = make_float4(a0, a1, a2, a3);
}

// ---------------- launch ----------------

extern "C" void kernel_launch(void* const* d_in, const int* in_sizes, int n_in,
                              void* d_out, int out_size, void* d_ws, size_t ws_size,
                              hipStream_t stream) {
    const float* x    = (const float*)d_in[0];
    const int*   eidx = (const int*)d_in[1];
    const float* ea   = (const float*)d_in[2];
    const float* W1   = (const float*)d_in[3];
    const float* b1   = (const float*)d_in[4];
    const float* W2   = (const float*)d_in[5];
    const float* b2   = (const float*)d_in[6];
    const float* W3   = (const float*)d_in[7];
    const float* b3   = (const float*)d_in[8];

    const int N = in_sizes[0] / 128;
    const int E = in_sizes[2];

    const int nbins = (N + 255) >> BIN_SHIFT;            // 196 for N=50000 (<=256)
    const int epb   = (E + SCAT_NB - 1) / SCAT_NB;       // edges per scatter block
    const int nbc   = nbins * SCAT_NB;                   // bcnt/ebofs length
    const int gBC   = (nbc + BLK - 1) / BLK;

    char*  base = (char*)d_ws;
    size_t off  = 0;
    auto carve = [&](size_t nbytes) -> void* {
        void* p = base + off;
        off = (off + nbytes + 255) & ~(size_t)255;
        return p;
    };
    int*   bcnt      = (int*)  carve((size_t)nbc * 4);
    int*   ebofs     = (int*)  carve((size_t)nbc * 4);
    int*   bsumB     = (int*)  carve((size_t)512 * 4);
    uint2* binned    = (uint2*)carve((size_t)E * 8);
    float* dinv      = (float*)carve((size_t)N * 4);
    int*   rowptr    = (int*)  carve((size_t)(N + 1) * 4);
    int*   csr_src   = (int*)  carve((size_t)E * 4);
    float* csr_val   = (float*)carve((size_t)E * 4);
    ushort_t* bufA   = (ushort_t*)carve((size_t)N * 128 * 2);   // bf16: H'1 / H'3
    ushort_t* bufB   = (ushort_t*)carve((size_t)N * 64 * 2);    // bf16: H'2
    ushort_t* Wt1    = (ushort_t*)carve((size_t)128 * 128 * 2);
    ushort_t* Wt2    = (ushort_t*)carve((size_t)64 * 128 * 2);
    ushort_t* Wt3    = (ushort_t*)carve((size_t)32 * 64 * 2);
    (void)ws_size;

    const int wtot = 128 * 128 + 128 * 64 + 64 * 32;
    const int gPre = SCAT_NB + (wtot + 255) / 256;
    const int gR  = (N + 127) / 128;                     // gemm1 blocks (128 rows/block)
    const int gF  = (N + 31) / 32;                       // fused agg+gemm blocks (32 rows)

    // preprocessing (5 dispatches, scan-based, no global atomics)
    k_pre<<<gPre, BLK, 0, stream>>>(eidx, bcnt, nbins, epb, E, W1, Wt1, W2, Wt2, W3, Wt3);
    k_scan1<<<gBC, BLK, 0, stream>>>(bcnt, ebofs, bsumB, nbc);
    k_scan2x<<<1, BLK, 0, stream>>>(bsumB, gBC);
    k_bin_scatter<<<SCAT_NB, BLK, 0, stream>>>(eidx, ea, ebofs, bsumB, binned, nbins, epb, E);
    k_bin_finish<<<nbins, BLK, 0, stream>>>(binned, ebofs, bsumB, dinv, rowptr,
                                            csr_src, csr_val, nbins, N, E);

    // layer 1 GEMM: H'1 = dinv * (x @ W1)   (reads f32 x directly)
    k_gemm_f32<128, 128><<<gR, BLK, 0, stream>>>(x, Wt1, dinv, bufA, N);

    // fused: G2 = relu(agg(H'1)+b1); H'2 = dinv*(G2 @ W2)
    k_agg_gemm<128, 64><<<gF, BLK, 0, stream>>>(bufA, dinv, rowptr, csr_src, csr_val,
                                                b1, Wt2, bufB, N);

    // fused: G3 = relu(agg(H'2)+b2); H'3 = dinv*(G3 @ W3)
    k_agg_gemm<64, 32><<<gF, BLK, 0, stream>>>(bufB, dinv, rowptr, csr_src, csr_val,
                                               b2, Wt3, bufA, N);

    // final: out = agg(H'3) + b3   (f32, no relu)
    k_agg_final<32><<<(N + 31) / 32, BLK, 0, stream>>>(bufA, dinv, rowptr, csr_src, csr_val,
                                                       b3, (float*)d_out, N);
}